// Round 6
// baseline (276.699 us; speedup 1.0000x reference)
//
#include <hip/hip_runtime.h>

typedef __attribute__((ext_vector_type(8))) short bf16x8;
typedef __attribute__((ext_vector_type(8))) _Float16 f16x8;
typedef __attribute__((ext_vector_type(2))) _Float16 f16x2;
typedef __attribute__((ext_vector_type(4))) float f32x4;

__device__ __forceinline__ unsigned short f2bf(float f) {
  union { float f; unsigned int i; } v;
  v.f = f;
  unsigned int r = v.i + 0x7FFFu + ((v.i >> 16) & 1u);  // RNE
  return (unsigned short)(r >> 16);
}

__device__ __forceinline__ f16x2 cvt_pk(float a, float b) {
  return __builtin_bit_cast(f16x2, __builtin_amdgcn_cvt_pkrtz(a, b));
}

// async global->LDS, 16B per lane. LDS dst is wave-uniform base + lane*16;
// global src must therefore be the fragment-element address of each lane.
__device__ __forceinline__ void gl_lds16(const unsigned short* g, unsigned short* l) {
  __builtin_amdgcn_global_load_lds(
      (const __attribute__((address_space(1))) unsigned int*)g,
      (__attribute__((address_space(3))) unsigned int*)l, 16, 0, 0);
}

// e^x on [-1,1], Chebyshev-truncated degree 5 (abs err ~5e-5), packed f16.
__device__ __forceinline__ f16x2 exp_poly(f16x2 x) {
  const f16x2 a5 = {(_Float16)0.00868682f, (_Float16)0.00868682f};
  const f16x2 a4 = {(_Float16)0.04379392f, (_Float16)0.04379392f};
  const f16x2 a3 = {(_Float16)0.16648887f, (_Float16)0.16648887f};
  const f16x2 a2 = {(_Float16)0.49919676f, (_Float16)0.49919676f};
  const f16x2 a1 = {(_Float16)1.00002229f, (_Float16)1.00002229f};
  const f16x2 a0 = {(_Float16)1.00004478f, (_Float16)1.00004478f};
#if __has_builtin(__builtin_elementwise_fma)
  f16x2 r = a5;
  r = __builtin_elementwise_fma(r, x, a4);
  r = __builtin_elementwise_fma(r, x, a3);
  r = __builtin_elementwise_fma(r, x, a2);
  r = __builtin_elementwise_fma(r, x, a1);
  r = __builtin_elementwise_fma(r, x, a0);
#else
  f16x2 r = a5;
  r = r * x + a4;
  r = r * x + a3;
  r = r * x + a2;
  r = r * x + a1;
  r = r * x + a0;
#endif
  return r;
}

__device__ __forceinline__ float dot2acc(f16x2 a, float acc) {
#if __has_builtin(__builtin_amdgcn_fdot2)
  const f16x2 one2 = {(_Float16)1.0f, (_Float16)1.0f};
  return __builtin_amdgcn_fdot2(a, one2, acc, false);
#else
  return acc + (float)a.x + (float)a.y;
#endif
}

// ---------------- fused fp32 -> bf16 convert for x, Wq, Wkv, Wo ----------------
__global__ __launch_bounds__(256) void cvt_all(
    const float* __restrict__ x, const float* __restrict__ wq,
    const float* __restrict__ wkv, const float* __restrict__ wo,
    unsigned short* __restrict__ xb, unsigned short* __restrict__ wqb,
    unsigned short* __restrict__ wkvb, unsigned short* __restrict__ wob) {
  int b = blockIdx.x;
  const float* in;
  unsigned short* out;
  int i;
  if (b < 8192) { in = x; out = xb; i = b * 256 + threadIdx.x; }
  else if (b < 8448) { in = wq; out = wqb; i = (b - 8192) * 256 + threadIdx.x; }
  else if (b < 8704) { in = wkv; out = wkvb; i = (b - 8448) * 256 + threadIdx.x; }
  else { in = wo; out = wob; i = (b - 8704) * 256 + threadIdx.x; }
  float4 v = ((const float4*)in)[i];
  ushort4 o;
  o.x = f2bf(v.x);
  o.y = f2bf(v.y);
  o.z = f2bf(v.z);
  o.w = f2bf(v.w);
  ((ushort4*)out)[i] = o;
}

// ---------------- fused Q + KV projection GEMM ----------------
// Fragment-major LDS + global_load_lds(16B) staging (m97 structure).
// A/B tiles stored as 16 fragments of 1 KB: slot = mblk*2 + ks, data at
// slot*512 + lane*8 shorts (lane's own 16 B).
// grid (128, 8): y<4 -> Q half (Qn bf16 normalized), y>=4 -> KV half
// (Kn bf16 normalized + Vt f16 transposed [g][d][s] from the accumulator).
__global__ __launch_bounds__(256) void gemm_qkv(
    const unsigned short* __restrict__ A, const unsigned short* __restrict__ Wq,
    const unsigned short* __restrict__ Wkv, const float* __restrict__ bq,
    const float* __restrict__ bkv, unsigned short* __restrict__ Qn,
    unsigned short* __restrict__ Vt, unsigned short* __restrict__ Kn) {
  __shared__ __attribute__((aligned(16))) unsigned short lA[16 * 512];
  __shared__ __attribute__((aligned(16))) unsigned short lB[16 * 512];
  const int isKV = (int)(blockIdx.y >> 2);
  const unsigned short* Bt = isKV ? Wkv : Wq;
  const float* bias = isKV ? bkv : bq;
  const int tid = threadIdx.x;
  const int lane = tid & 63;
  const int quad = lane >> 4, m16 = lane & 15;
  const int w = tid >> 6;
  const int wm = w >> 1, wn = w & 1;
  const long mb = (long)blockIdx.x * 128;
  const long nb = (long)(blockIdx.y & 3) * 128;
  f32x4 acc[4][4];
#pragma unroll
  for (int i = 0; i < 4; i++)
#pragma unroll
    for (int j = 0; j < 4; j++) acc[i][j] = (f32x4){0.f, 0.f, 0.f, 0.f};

  for (int kb = 0; kb < 512; kb += 64) {
    __syncthreads();
    // wave w stages A mblk {2w,2w+1} and B nblk {2w,2w+1}, both ks
    {
      const unsigned short* gA = A + (mb + (2 * w) * 16 + m16) * 512 + kb + quad * 8;
      gl_lds16(gA, &lA[(4 * w + 0) * 512]);
      gl_lds16(gA + 32, &lA[(4 * w + 1) * 512]);
      gl_lds16(gA + 16 * 512, &lA[(4 * w + 2) * 512]);
      gl_lds16(gA + 16 * 512 + 32, &lA[(4 * w + 3) * 512]);
      const unsigned short* gB = Bt + (nb + (2 * w) * 16 + m16) * 512 + kb + quad * 8;
      gl_lds16(gB, &lB[(4 * w + 0) * 512]);
      gl_lds16(gB + 32, &lB[(4 * w + 1) * 512]);
      gl_lds16(gB + 16 * 512, &lB[(4 * w + 2) * 512]);
      gl_lds16(gB + 16 * 512 + 32, &lB[(4 * w + 3) * 512]);
    }
    __syncthreads();
#pragma unroll
    for (int ks = 0; ks < 2; ks++) {
      bf16x8 af[4], bfr[4];
#pragma unroll
      for (int i = 0; i < 4; i++)
        af[i] = *(const bf16x8*)&lA[(((wm * 4 + i) << 1) | ks) * 512 + lane * 8];
#pragma unroll
      for (int j = 0; j < 4; j++)
        bfr[j] = *(const bf16x8*)&lB[(((wn * 4 + j) << 1) | ks) * 512 + lane * 8];
#pragma unroll
      for (int i = 0; i < 4; i++)
#pragma unroll
        for (int j = 0; j < 4; j++)
          acc[i][j] =
              __builtin_amdgcn_mfma_f32_16x16x32_bf16(af[i], bfr[j], acc[i][j], 0, 0, 0);
    }
  }
#pragma unroll
  for (int i = 0; i < 4; i++) {
    long row0 = mb + wm * 64 + i * 16 + quad * 4;
    float bb[4], val[4][4], inv[4];
#pragma unroll
    for (int j = 0; j < 4; j++) {
      bb[j] = bias[nb + wn * 64 + j * 16 + m16];
#pragma unroll
      for (int r = 0; r < 4; r++) val[j][r] = acc[i][j][r] + bb[j];
    }
#pragma unroll
    for (int r = 0; r < 4; r++) {
      float s = val[0][r] * val[0][r] + val[1][r] * val[1][r] +
                val[2][r] * val[2][r] + val[3][r] * val[3][r];
      s += __shfl_xor(s, 1);
      s += __shfl_xor(s, 2);
      s += __shfl_xor(s, 4);
      s += __shfl_xor(s, 8);
      inv[r] = 1.0f / fmaxf(sqrtf(s), 1e-12f);
    }
    if (!isKV) {
#pragma unroll
      for (int r = 0; r < 4; r++)
#pragma unroll
        for (int j = 0; j < 4; j++) {
          long col = nb + wn * 64 + j * 16 + m16;
          Qn[(row0 + r) * 512 + col] = f2bf(val[j][r] * inv[r]);
        }
    } else {
#pragma unroll
      for (int r = 0; r < 4; r++)
#pragma unroll
        for (int j = 0; j < 4; j++) {
          long col = nb + wn * 64 + j * 16 + m16;
          Kn[(row0 + r) * 512 + col] = f2bf(val[j][r] * inv[r]);
        }
      // V^T: 4 consecutive s per lane for fixed (g,d) -> one 8B f16 store
      int bm = (int)(row0 >> 11);
      int s0 = (int)(row0 & 2047);
#pragma unroll
      for (int j = 0; j < 4; j++) {
        int col = (int)(nb) + wn * 64 + j * 16 + m16;
        int h = col >> 6, d = col & 63;
        f16x2 lo = cvt_pk(val[j][0], val[j][1]);
        f16x2 hi = cvt_pk(val[j][2], val[j][3]);
        uint2 pk = make_uint2(__builtin_bit_cast(unsigned int, lo),
                              __builtin_bit_cast(unsigned int, hi));
        *(uint2*)(Vt + ((long)(bm * 8 + h) * 64 + d) * 2048 + s0) = pk;
      }
    }
  }
}

// ---------------- output projection GEMM (bf16 in, f32 out) ----------------
__global__ __launch_bounds__(256) void gemm_o(
    const unsigned short* __restrict__ A, const unsigned short* __restrict__ Bt,
    const float* __restrict__ bias, float* __restrict__ Cout) {
  __shared__ __attribute__((aligned(16))) unsigned short lA[16 * 512];
  __shared__ __attribute__((aligned(16))) unsigned short lB[16 * 512];
  const int tid = threadIdx.x;
  const int lane = tid & 63;
  const int quad = lane >> 4, m16 = lane & 15;
  const int w = tid >> 6;
  const int wm = w >> 1, wn = w & 1;
  const long mb = (long)blockIdx.x * 128;
  const long nb = (long)blockIdx.y * 128;
  f32x4 acc[4][4];
#pragma unroll
  for (int i = 0; i < 4; i++)
#pragma unroll
    for (int j = 0; j < 4; j++) acc[i][j] = (f32x4){0.f, 0.f, 0.f, 0.f};

  for (int kb = 0; kb < 512; kb += 64) {
    __syncthreads();
    {
      const unsigned short* gA = A + (mb + (2 * w) * 16 + m16) * 512 + kb + quad * 8;
      gl_lds16(gA, &lA[(4 * w + 0) * 512]);
      gl_lds16(gA + 32, &lA[(4 * w + 1) * 512]);
      gl_lds16(gA + 16 * 512, &lA[(4 * w + 2) * 512]);
      gl_lds16(gA + 16 * 512 + 32, &lA[(4 * w + 3) * 512]);
      const unsigned short* gB = Bt + (nb + (2 * w) * 16 + m16) * 512 + kb + quad * 8;
      gl_lds16(gB, &lB[(4 * w + 0) * 512]);
      gl_lds16(gB + 32, &lB[(4 * w + 1) * 512]);
      gl_lds16(gB + 16 * 512, &lB[(4 * w + 2) * 512]);
      gl_lds16(gB + 16 * 512 + 32, &lB[(4 * w + 3) * 512]);
    }
    __syncthreads();
#pragma unroll
    for (int ks = 0; ks < 2; ks++) {
      bf16x8 af[4], bfr[4];
#pragma unroll
      for (int i = 0; i < 4; i++)
        af[i] = *(const bf16x8*)&lA[(((wm * 4 + i) << 1) | ks) * 512 + lane * 8];
#pragma unroll
      for (int j = 0; j < 4; j++)
        bfr[j] = *(const bf16x8*)&lB[(((wn * 4 + j) << 1) | ks) * 512 + lane * 8];
#pragma unroll
      for (int i = 0; i < 4; i++)
#pragma unroll
        for (int j = 0; j < 4; j++)
          acc[i][j] =
              __builtin_amdgcn_mfma_f32_16x16x32_bf16(af[i], bfr[j], acc[i][j], 0, 0, 0);
    }
  }
#pragma unroll
  for (int i = 0; i < 4; i++) {
    long row0 = mb + wm * 64 + i * 16 + quad * 4;
#pragma unroll
    for (int j = 0; j < 4; j++) {
      long col = nb + wn * 64 + j * 16 + m16;
      float bb = bias[col];
#pragma unroll
      for (int r = 0; r < 4; r++) Cout[(row0 + r) * 512 + col] = acc[i][j][r] + bb;
    }
  }
}

// ---------------- cosine attention ----------------
// Fragment-major lK/lVt staged by async global_load_lds (4 per wave per
// k-tile); lP XOR-swizzled 64-short rows (2-way banks = free). 32 KB LDS
// -> 5 blocks/CU. S^T = Kn @ Qn^T; packed-f16 poly exp; PV in f16 MFMA.
__global__ __launch_bounds__(256, 5) void attn_cos(
    const unsigned short* __restrict__ Qn, const unsigned short* __restrict__ Kn,
    const unsigned short* __restrict__ Vt, unsigned short* __restrict__ ctx) {
  __shared__ __attribute__((aligned(16))) unsigned short lK[8 * 512];   // 8 KB
  __shared__ __attribute__((aligned(16))) unsigned short lVt[8 * 512];  // 8 KB
  __shared__ __attribute__((aligned(16))) unsigned short lP[128 * 64];  // 16 KB
  const int qt = blockIdx.x;  // 0..15
  const int g = blockIdx.y;   // 0..63
  const int bm = g >> 3, h = g & 7;
  const int tid = threadIdx.x;
  const int lane = tid & 63;
  const int quad = lane >> 4, m16 = lane & 15;
  const int w = tid >> 6;
  const long rowbase = (long)bm * 2048;
  const int colbase = h * 64;
  const long qrow0 = rowbase + qt * 128 + w * 32;
  const unsigned short* Kbase = Kn + rowbase * 512 + colbase;
  const unsigned short* Vbase = Vt + (long)g * 64 * 2048;
  const int swz = (m16 & 7) << 3;  // lP XOR swizzle key (multiple of 8)

  // Q B-fragments (fixed for all k-tiles)
  bf16x8 qf[2][2];
#pragma unroll
  for (int i = 0; i < 2; i++)
#pragma unroll
    for (int ks = 0; ks < 2; ks++)
      qf[i][ks] = *(const bf16x8*)(Qn + (qrow0 + i * 16 + m16) * 512 + colbase +
                                   ks * 32 + quad * 8);

  f32x4 cacc[2][4];
#pragma unroll
  for (int i = 0; i < 2; i++)
#pragma unroll
    for (int j = 0; j < 4; j++) cacc[i][j] = (f32x4){0.f, 0.f, 0.f, 0.f};
  float li[2] = {0.f, 0.f};

  for (int kt = 0; kt < 32; ++kt) {
    __syncthreads();
    // wave w stages K-frags (j=w, ks=0/1) and V-frags (j=w, ks=0/1)
    {
      const unsigned short* gK = Kbase + (kt * 64 + w * 16 + m16) * 512 + quad * 8;
      gl_lds16(gK, &lK[(2 * w + 0) * 512]);
      gl_lds16(gK + 32, &lK[(2 * w + 1) * 512]);
      const unsigned short* gV = Vbase + (w * 16 + m16) * 2048 + kt * 64 + quad * 8;
      gl_lds16(gV, &lVt[(2 * w + 0) * 512]);
      gl_lds16(gV + 32, &lVt[(2 * w + 1) * 512]);
    }
    __syncthreads();

    // S^T[k][q]: A = Kn frag (m=k), B = Q frag (n=q), contraction d=64
    f32x4 sacc[4][2];
#pragma unroll
    for (int j = 0; j < 4; j++)
#pragma unroll
      for (int i = 0; i < 2; i++) sacc[j][i] = (f32x4){0.f, 0.f, 0.f, 0.f};
#pragma unroll
    for (int ks = 0; ks < 2; ++ks) {
      bf16x8 kf[4];
#pragma unroll
      for (int j = 0; j < 4; j++)
        kf[j] = *(const bf16x8*)&lK[((j << 1) | ks) * 512 + lane * 8];
#pragma unroll
      for (int j = 0; j < 4; j++)
#pragma unroll
        for (int i = 0; i < 2; i++)
          sacc[j][i] =
              __builtin_amdgcn_mfma_f32_16x16x32_bf16(kf[j], qf[i][ks], sacc[j][i], 0, 0, 0);
    }

    // packed-f16 exp + li + swizzled P write.
    // Lane: q = i*16+m16 (row), k = j*16 + quad*4 + (0..3)
#pragma unroll
    for (int j = 0; j < 4; j++)
#pragma unroll
      for (int i = 0; i < 2; i++) {
        f16x2 x01 = cvt_pk(sacc[j][i][0], sacc[j][i][1]);
        f16x2 x23 = cvt_pk(sacc[j][i][2], sacc[j][i][3]);
        f16x2 e01 = exp_poly(x01);
        f16x2 e23 = exp_poly(x23);
        li[i] = dot2acc(e01, li[i]);
        li[i] = dot2acc(e23, li[i]);
        uint2 pk = make_uint2(__builtin_bit_cast(unsigned int, e01),
                              __builtin_bit_cast(unsigned int, e23));
        *(uint2*)&lP[(w * 32 + i * 16 + m16) * 64 + ((j * 16 + quad * 4) ^ swz)] = pk;
      }

    // PV (f16): ctx[q][d] += P @ V, contraction k=64 (wave-private lP rows)
#pragma unroll
    for (int ks = 0; ks < 2; ++ks) {
      f16x8 pf[2], vf[4];
#pragma unroll
      for (int i = 0; i < 2; i++)
        pf[i] = *(const f16x8*)&lP[(w * 32 + i * 16 + m16) * 64 +
                                   ((ks * 32 + quad * 8) ^ swz)];
#pragma unroll
      for (int j = 0; j < 4; j++)
        vf[j] = *(const f16x8*)&lVt[((j << 1) | ks) * 512 + lane * 8];
#pragma unroll
      for (int i = 0; i < 2; i++)
#pragma unroll
        for (int j = 0; j < 4; j++)
          cacc[i][j] =
              __builtin_amdgcn_mfma_f32_16x16x32_f16(pf[i], vf[j], cacc[i][j], 0, 0, 0);
    }
  }

  // reduce li across quads (lanes sharing m16)
#pragma unroll
  for (int i = 0; i < 2; i++) {
    li[i] += __shfl_xor(li[i], 16);
    li[i] += __shfl_xor(li[i], 32);
  }
  float linv[2][4];
#pragma unroll
  for (int i = 0; i < 2; i++)
#pragma unroll
    for (int r = 0; r < 4; r++) linv[i][r] = 1.0f / __shfl(li[i], quad * 4 + r);
#pragma unroll
  for (int i = 0; i < 2; i++)
#pragma unroll
    for (int j = 0; j < 4; j++) {
      long dcol = colbase + j * 16 + m16;
#pragma unroll
      for (int r = 0; r < 4; r++) {
        long qrow = qrow0 + i * 16 + quad * 4 + r;
        ctx[qrow * 512 + dcol] = f2bf(cacc[i][j][r] * linv[i][r]);
      }
    }
}

extern "C" void kernel_launch(void* const* d_in, const int* in_sizes, int n_in,
                              void* d_out, int out_size, void* d_ws, size_t ws_size,
                              hipStream_t stream) {
  (void)in_sizes; (void)n_in; (void)out_size; (void)ws_size;
  const float* x = (const float*)d_in[0];
  const float* Wq = (const float*)d_in[1];
  const float* bq = (const float*)d_in[2];
  const float* Wkv = (const float*)d_in[3];
  const float* bkv = (const float*)d_in[4];
  const float* Wo = (const float*)d_in[5];
  const float* bo = (const float*)d_in[6];

  char* ws = (char*)d_ws;
  unsigned short* x_bf   = (unsigned short*)(ws);             // 16 MiB (reused as ctx)
  unsigned short* Wq_bf  = (unsigned short*)(ws + 16777216);  // 512 KiB
  unsigned short* Wkv_bf = (unsigned short*)(ws + 17301504);  // 512 KiB
  unsigned short* Wo_bf  = (unsigned short*)(ws + 17825792);  // 512 KiB
  unsigned short* Qn_bf  = (unsigned short*)(ws + 18350080);  // 16 MiB
  unsigned short* Kn_bf  = (unsigned short*)(ws + 35127296);  // 16 MiB
  unsigned short* Vt_f16 = (unsigned short*)(ws + 51904512);  // 16 MiB
  unsigned short* ctx_bf = x_bf;  // x dead after gemm_qkv

  cvt_all<<<8960, 256, 0, stream>>>(x, Wq, Wkv, Wo, x_bf, Wq_bf, Wkv_bf, Wo_bf);

  gemm_qkv<<<dim3(128, 8), 256, 0, stream>>>(x_bf, Wq_bf, Wkv_bf, bq, bkv, Qn_bf,
                                             Vt_f16, Kn_bf);

  attn_cos<<<dim3(16, 64), 256, 0, stream>>>(Qn_bf, Kn_bf, Vt_f16, ctx_bf);

  gemm_o<<<dim3(128, 4), 256, 0, stream>>>(ctx_bf, Wo_bf, bo, (float*)d_out);
}

// Round 7
// 228.864 us; speedup vs baseline: 1.2090x; 1.2090x over previous
//
#include <hip/hip_runtime.h>

typedef __attribute__((ext_vector_type(8))) short bf16x8;
typedef __attribute__((ext_vector_type(8))) _Float16 f16x8;
typedef __attribute__((ext_vector_type(2))) _Float16 f16x2;
typedef __attribute__((ext_vector_type(4))) float f32x4;

__device__ __forceinline__ unsigned short f2bf(float f) {
  union { float f; unsigned int i; } v;
  v.f = f;
  unsigned int r = v.i + 0x7FFFu + ((v.i >> 16) & 1u);  // RNE
  return (unsigned short)(r >> 16);
}

__device__ __forceinline__ f16x2 cvt_pk(float a, float b) {
  return __builtin_bit_cast(f16x2, __builtin_amdgcn_cvt_pkrtz(a, b));
}

// async global->LDS, 16B/lane. LDS dst = wave-uniform base + lane*16.
// Global src MUST be base + lane*16 (contiguous 1KB) for full coalescing —
// all layouts below are fragment-major to guarantee this.
__device__ __forceinline__ void gl_lds16(const unsigned short* g, unsigned short* l) {
  __builtin_amdgcn_global_load_lds(
      (const __attribute__((address_space(1))) unsigned int*)g,
      (__attribute__((address_space(3))) unsigned int*)l, 16, 0, 0);
}

// e^x on [-1,1], Chebyshev-truncated degree 5 (abs err ~5e-5), packed f16.
__device__ __forceinline__ f16x2 exp_poly(f16x2 x) {
  const f16x2 a5 = {(_Float16)0.00868682f, (_Float16)0.00868682f};
  const f16x2 a4 = {(_Float16)0.04379392f, (_Float16)0.04379392f};
  const f16x2 a3 = {(_Float16)0.16648887f, (_Float16)0.16648887f};
  const f16x2 a2 = {(_Float16)0.49919676f, (_Float16)0.49919676f};
  const f16x2 a1 = {(_Float16)1.00002229f, (_Float16)1.00002229f};
  const f16x2 a0 = {(_Float16)1.00004478f, (_Float16)1.00004478f};
#if __has_builtin(__builtin_elementwise_fma)
  f16x2 r = a5;
  r = __builtin_elementwise_fma(r, x, a4);
  r = __builtin_elementwise_fma(r, x, a3);
  r = __builtin_elementwise_fma(r, x, a2);
  r = __builtin_elementwise_fma(r, x, a1);
  r = __builtin_elementwise_fma(r, x, a0);
#else
  f16x2 r = a5;
  r = r * x + a4;
  r = r * x + a3;
  r = r * x + a2;
  r = r * x + a1;
  r = r * x + a0;
#endif
  return r;
}

__device__ __forceinline__ float dot2acc(f16x2 a, float acc) {
#if __has_builtin(__builtin_amdgcn_fdot2)
  const f16x2 one2 = {(_Float16)1.0f, (_Float16)1.0f};
  return __builtin_amdgcn_fdot2(a, one2, acc, false);
#else
  return acc + (float)a.x + (float)a.y;
#endif
}

// ---------------- fp32 -> bf16 convert to FRAGMENT-MAJOR layout ----------------
// Layout: [rtile(=row>>7)][kb(=c>>6)][slot(=((row>>4)&7)*2+((c>>5)&1))]
//         [lane(=((c>>3)&3)*16+(row&15))][e(=c&7)]   (shorts)
__global__ __launch_bounds__(256) void cvt_all(
    const float* __restrict__ x, const float* __restrict__ wq,
    const float* __restrict__ wkv, const float* __restrict__ wo,
    unsigned short* __restrict__ xf, unsigned short* __restrict__ wqf,
    unsigned short* __restrict__ wkvf, unsigned short* __restrict__ wof) {
  int b = blockIdx.x;
  const float* in;
  unsigned short* out;
  int i;
  if (b < 8192) { in = x; out = xf; i = b * 256 + threadIdx.x; }
  else if (b < 8448) { in = wq; out = wqf; i = (b - 8192) * 256 + threadIdx.x; }
  else if (b < 8704) { in = wkv; out = wkvf; i = (b - 8448) * 256 + threadIdx.x; }
  else { in = wo; out = wof; i = (b - 8704) * 256 + threadIdx.x; }
  float4 v = ((const float4*)in)[i];
  int f = i << 2;
  int row = f >> 9, c = f & 511;
  long off = ((((long)(row >> 7) * 8 + (c >> 6)) * 16 + ((row >> 4) & 7) * 2 +
               ((c >> 5) & 1)) * 64 + ((c >> 3) & 3) * 16 + (row & 15)) * 8 + (c & 7);
  ushort4 o;
  o.x = f2bf(v.x);
  o.y = f2bf(v.y);
  o.z = f2bf(v.z);
  o.w = f2bf(v.w);
  *(ushort4*)(out + off) = o;
}

// ---------------- fused Q + KV projection GEMM (fragment-major in) ----------------
// grid (128, 8): y<4 -> Q half (Qn bf16 normalized, row-major),
// y>=4 -> KV half (Kf bf16 normalized fragment-major + Vf f16 V^T fragment-major).
// Kf/Vf layout: [(g*32+kt)*8 + slot][lane][8] shorts, 1KB per slot.
__global__ __launch_bounds__(256) void gemm_qkv(
    const unsigned short* __restrict__ xf, const unsigned short* __restrict__ Wqf,
    const unsigned short* __restrict__ Wkvf, const float* __restrict__ bq,
    const float* __restrict__ bkv, unsigned short* __restrict__ Qn,
    unsigned short* __restrict__ Kf, unsigned short* __restrict__ Vf) {
  __shared__ __attribute__((aligned(16))) unsigned short lA[16 * 512];
  __shared__ __attribute__((aligned(16))) unsigned short lB[16 * 512];
  const int isKV = (int)(blockIdx.y >> 2);
  const unsigned short* Btf = isKV ? Wkvf : Wqf;
  const float* bias = isKV ? bkv : bq;
  const int tid = threadIdx.x;
  const int lane = tid & 63;
  const int quad = lane >> 4, m16 = lane & 15;
  const int w = tid >> 6;
  const int wm = w >> 1, wn = w & 1;
  const long mb = (long)blockIdx.x * 128;
  const int nt = (int)(blockIdx.y & 3);
  const long nb = (long)nt * 128;
  f32x4 acc[4][4];
#pragma unroll
  for (int i = 0; i < 4; i++)
#pragma unroll
    for (int j = 0; j < 4; j++) acc[i][j] = (f32x4){0.f, 0.f, 0.f, 0.f};

  for (int kb = 0; kb < 8; kb++) {
    __syncthreads();
    {
      const unsigned short* gA =
          xf + (((long)blockIdx.x * 8 + kb) * 16 + 4 * w) * 512 + lane * 8;
      gl_lds16(gA, &lA[(4 * w + 0) * 512]);
      gl_lds16(gA + 512, &lA[(4 * w + 1) * 512]);
      gl_lds16(gA + 1024, &lA[(4 * w + 2) * 512]);
      gl_lds16(gA + 1536, &lA[(4 * w + 3) * 512]);
      const unsigned short* gB =
          Btf + (((long)nt * 8 + kb) * 16 + 4 * w) * 512 + lane * 8;
      gl_lds16(gB, &lB[(4 * w + 0) * 512]);
      gl_lds16(gB + 512, &lB[(4 * w + 1) * 512]);
      gl_lds16(gB + 1024, &lB[(4 * w + 2) * 512]);
      gl_lds16(gB + 1536, &lB[(4 * w + 3) * 512]);
    }
    __syncthreads();
#pragma unroll
    for (int ks = 0; ks < 2; ks++) {
      bf16x8 af[4], bfr[4];
#pragma unroll
      for (int i = 0; i < 4; i++)
        af[i] = *(const bf16x8*)&lA[(((wm * 4 + i) << 1) | ks) * 512 + lane * 8];
#pragma unroll
      for (int j = 0; j < 4; j++)
        bfr[j] = *(const bf16x8*)&lB[(((wn * 4 + j) << 1) | ks) * 512 + lane * 8];
#pragma unroll
      for (int i = 0; i < 4; i++)
#pragma unroll
        for (int j = 0; j < 4; j++)
          acc[i][j] =
              __builtin_amdgcn_mfma_f32_16x16x32_bf16(af[i], bfr[j], acc[i][j], 0, 0, 0);
    }
  }
  const int h = (int)(nb >> 6) + wn;  // head is constant per wave-column
#pragma unroll
  for (int i = 0; i < 4; i++) {
    long row0 = mb + wm * 64 + i * 16 + quad * 4;
    float bb[4], val[4][4], inv[4];
#pragma unroll
    for (int j = 0; j < 4; j++) {
      bb[j] = bias[nb + wn * 64 + j * 16 + m16];
#pragma unroll
      for (int r = 0; r < 4; r++) val[j][r] = acc[i][j][r] + bb[j];
    }
#pragma unroll
    for (int r = 0; r < 4; r++) {
      float s = val[0][r] * val[0][r] + val[1][r] * val[1][r] +
                val[2][r] * val[2][r] + val[3][r] * val[3][r];
      s += __shfl_xor(s, 1);
      s += __shfl_xor(s, 2);
      s += __shfl_xor(s, 4);
      s += __shfl_xor(s, 8);
      inv[r] = 1.0f / fmaxf(sqrtf(s), 1e-12f);
    }
    if (!isKV) {
#pragma unroll
      for (int r = 0; r < 4; r++)
#pragma unroll
        for (int j = 0; j < 4; j++) {
          long col = nb + wn * 64 + j * 16 + m16;
          Qn[(row0 + r) * 512 + col] = f2bf(val[j][r] * inv[r]);
        }
    } else {
      const int bm = (int)(row0 >> 11);
      const int g = bm * 8 + h;
      const int kt = (int)((row0 & 2047) >> 6);
      const long tb = ((long)g * 32 + kt) * 8;
      // Kf: element (s,d): slot = i*2+(d>>5), lane = ((d>>3)&3)*16 + (s&15), e = d&7
      //     here d = j*16+m16 -> (d>>5)=j>>1, (d>>3)&3 = ((j&1)<<1)|(m16>>3)
#pragma unroll
      for (int j = 0; j < 4; j++) {
        long kb0 = (tb + i * 2 + (j >> 1)) * 512 +
                   (((((j & 1) << 1) | (m16 >> 3)) * 16 + quad * 4) * 8) + (m16 & 7);
#pragma unroll
        for (int r = 0; r < 4; r++) Kf[kb0 + r * 8] = f2bf(val[j][r] * inv[r]);
      }
      // Vf (V^T): element (d,k): slot = j*2+(i>>1),
      //   lane = (((i&1)<<1)|(quad>>1))*16 + m16, e = (quad&1)*4 + r (contiguous!)
#pragma unroll
      for (int j = 0; j < 4; j++) {
        long vo = (tb + j * 2 + (i >> 1)) * 512 +
                  ((((((i & 1) << 1) | (quad >> 1)) * 16 + m16)) * 8) + (quad & 1) * 4;
        f16x2 lo = cvt_pk(val[j][0], val[j][1]);
        f16x2 hi = cvt_pk(val[j][2], val[j][3]);
        uint2 pk = make_uint2(__builtin_bit_cast(unsigned int, lo),
                              __builtin_bit_cast(unsigned int, hi));
        *(uint2*)(Vf + vo) = pk;
      }
    }
  }
}

// ---------------- output projection GEMM (fragment-major in, f32 out) ----------------
__global__ __launch_bounds__(256) void gemm_o(
    const unsigned short* __restrict__ Af, const unsigned short* __restrict__ Btf,
    const float* __restrict__ bias, float* __restrict__ Cout) {
  __shared__ __attribute__((aligned(16))) unsigned short lA[16 * 512];
  __shared__ __attribute__((aligned(16))) unsigned short lB[16 * 512];
  const int tid = threadIdx.x;
  const int lane = tid & 63;
  const int quad = lane >> 4, m16 = lane & 15;
  const int w = tid >> 6;
  const int wm = w >> 1, wn = w & 1;
  const long mb = (long)blockIdx.x * 128;
  const int nt = (int)blockIdx.y;
  const long nb = (long)nt * 128;
  f32x4 acc[4][4];
#pragma unroll
  for (int i = 0; i < 4; i++)
#pragma unroll
    for (int j = 0; j < 4; j++) acc[i][j] = (f32x4){0.f, 0.f, 0.f, 0.f};

  for (int kb = 0; kb < 8; kb++) {
    __syncthreads();
    {
      const unsigned short* gA =
          Af + (((long)blockIdx.x * 8 + kb) * 16 + 4 * w) * 512 + lane * 8;
      gl_lds16(gA, &lA[(4 * w + 0) * 512]);
      gl_lds16(gA + 512, &lA[(4 * w + 1) * 512]);
      gl_lds16(gA + 1024, &lA[(4 * w + 2) * 512]);
      gl_lds16(gA + 1536, &lA[(4 * w + 3) * 512]);
      const unsigned short* gB =
          Btf + (((long)nt * 8 + kb) * 16 + 4 * w) * 512 + lane * 8;
      gl_lds16(gB, &lB[(4 * w + 0) * 512]);
      gl_lds16(gB + 512, &lB[(4 * w + 1) * 512]);
      gl_lds16(gB + 1024, &lB[(4 * w + 2) * 512]);
      gl_lds16(gB + 1536, &lB[(4 * w + 3) * 512]);
    }
    __syncthreads();
#pragma unroll
    for (int ks = 0; ks < 2; ks++) {
      bf16x8 af[4], bfr[4];
#pragma unroll
      for (int i = 0; i < 4; i++)
        af[i] = *(const bf16x8*)&lA[(((wm * 4 + i) << 1) | ks) * 512 + lane * 8];
#pragma unroll
      for (int j = 0; j < 4; j++)
        bfr[j] = *(const bf16x8*)&lB[(((wn * 4 + j) << 1) | ks) * 512 + lane * 8];
#pragma unroll
      for (int i = 0; i < 4; i++)
#pragma unroll
        for (int j = 0; j < 4; j++)
          acc[i][j] =
              __builtin_amdgcn_mfma_f32_16x16x32_bf16(af[i], bfr[j], acc[i][j], 0, 0, 0);
    }
  }
#pragma unroll
  for (int i = 0; i < 4; i++) {
    long row0 = mb + wm * 64 + i * 16 + quad * 4;
#pragma unroll
    for (int j = 0; j < 4; j++) {
      long col = nb + wn * 64 + j * 16 + m16;
      float bb = bias[col];
#pragma unroll
      for (int r = 0; r < 4; r++) Cout[(row0 + r) * 512 + col] = acc[i][j][r] + bb;
    }
  }
}

// ---------------- cosine attention ----------------
// K/V tiles staged via fully-coalesced gl_lds16 from fragment-major Kf/Vf.
// S^T = Kn @ Qn^T; packed-f16 poly exp; PV in f16 MFMA; lP XOR-swizzled.
// Epilogue writes ctx fragment-major for gemm_o.
__global__ __launch_bounds__(256, 4) void attn_cos(
    const unsigned short* __restrict__ Qn, const unsigned short* __restrict__ Kf,
    const unsigned short* __restrict__ Vf, unsigned short* __restrict__ ctxf) {
  __shared__ __attribute__((aligned(16))) unsigned short lK[8 * 512];   // 8 KB
  __shared__ __attribute__((aligned(16))) unsigned short lVt[8 * 512];  // 8 KB
  __shared__ __attribute__((aligned(16))) unsigned short lP[128 * 64];  // 16 KB
  const int qt = blockIdx.x;  // 0..15
  const int g = blockIdx.y;   // 0..63
  const int bm = g >> 3, h = g & 7;
  const int tid = threadIdx.x;
  const int lane = tid & 63;
  const int quad = lane >> 4, m16 = lane & 15;
  const int w = tid >> 6;
  const long rowbase = (long)bm * 2048;
  const int colbase = h * 64;
  const long qrow0 = rowbase + qt * 128 + w * 32;
  const int swz = (m16 & 7) << 3;  // lP XOR swizzle key

  // Q B-fragments (fixed for all k-tiles; one-time strided load, row-major Qn)
  bf16x8 qf[2][2];
#pragma unroll
  for (int i = 0; i < 2; i++)
#pragma unroll
    for (int ks = 0; ks < 2; ks++)
      qf[i][ks] = *(const bf16x8*)(Qn + (qrow0 + i * 16 + m16) * 512 + colbase +
                                   ks * 32 + quad * 8);

  f32x4 cacc[2][4];
#pragma unroll
  for (int i = 0; i < 2; i++)
#pragma unroll
    for (int j = 0; j < 4; j++) cacc[i][j] = (f32x4){0.f, 0.f, 0.f, 0.f};
  float li[2] = {0.f, 0.f};

  for (int kt = 0; kt < 32; ++kt) {
    const long tb = ((long)g * 32 + kt) * 8;
    __syncthreads();
    {
      const unsigned short* gK = Kf + (tb + 2 * w) * 512 + lane * 8;
      gl_lds16(gK, &lK[(2 * w + 0) * 512]);
      gl_lds16(gK + 512, &lK[(2 * w + 1) * 512]);
      const unsigned short* gV = Vf + (tb + 2 * w) * 512 + lane * 8;
      gl_lds16(gV, &lVt[(2 * w + 0) * 512]);
      gl_lds16(gV + 512, &lVt[(2 * w + 1) * 512]);
    }
    __syncthreads();

    // S^T[k][q]: A = Kn frag (m=k), B = Q frag (n=q), contraction d=64
    f32x4 sacc[4][2];
#pragma unroll
    for (int j = 0; j < 4; j++)
#pragma unroll
      for (int i = 0; i < 2; i++) sacc[j][i] = (f32x4){0.f, 0.f, 0.f, 0.f};
#pragma unroll
    for (int ks = 0; ks < 2; ++ks) {
      bf16x8 kf[4];
#pragma unroll
      for (int j = 0; j < 4; j++)
        kf[j] = *(const bf16x8*)&lK[((j << 1) | ks) * 512 + lane * 8];
#pragma unroll
      for (int j = 0; j < 4; j++)
#pragma unroll
        for (int i = 0; i < 2; i++)
          sacc[j][i] =
              __builtin_amdgcn_mfma_f32_16x16x32_bf16(kf[j], qf[i][ks], sacc[j][i], 0, 0, 0);
    }

    // packed-f16 exp + li + swizzled P write.
#pragma unroll
    for (int j = 0; j < 4; j++)
#pragma unroll
      for (int i = 0; i < 2; i++) {
        f16x2 x01 = cvt_pk(sacc[j][i][0], sacc[j][i][1]);
        f16x2 x23 = cvt_pk(sacc[j][i][2], sacc[j][i][3]);
        f16x2 e01 = exp_poly(x01);
        f16x2 e23 = exp_poly(x23);
        li[i] = dot2acc(e01, li[i]);
        li[i] = dot2acc(e23, li[i]);
        uint2 pk = make_uint2(__builtin_bit_cast(unsigned int, e01),
                              __builtin_bit_cast(unsigned int, e23));
        *(uint2*)&lP[(w * 32 + i * 16 + m16) * 64 + ((j * 16 + quad * 4) ^ swz)] = pk;
      }

    // PV (f16): ctx[q][d] += P @ V (wave-private lP rows, no barrier)
#pragma unroll
    for (int ks = 0; ks < 2; ++ks) {
      f16x8 pf[2], vf[4];
#pragma unroll
      for (int i = 0; i < 2; i++)
        pf[i] = *(const f16x8*)&lP[(w * 32 + i * 16 + m16) * 64 +
                                   ((ks * 32 + quad * 8) ^ swz)];
#pragma unroll
      for (int j = 0; j < 4; j++)
        vf[j] = *(const f16x8*)&lVt[((j << 1) | ks) * 512 + lane * 8];
#pragma unroll
      for (int i = 0; i < 2; i++)
#pragma unroll
        for (int j = 0; j < 4; j++)
          cacc[i][j] =
              __builtin_amdgcn_mfma_f32_16x16x32_f16(pf[i], vf[j], cacc[i][j], 0, 0, 0);
    }
  }

  // reduce li across quads (lanes sharing m16)
#pragma unroll
  for (int i = 0; i < 2; i++) {
    li[i] += __shfl_xor(li[i], 16);
    li[i] += __shfl_xor(li[i], 32);
  }
  float linv[2][4];
#pragma unroll
  for (int i = 0; i < 2; i++)
#pragma unroll
    for (int r = 0; r < 4; r++) linv[i][r] = 1.0f / __shfl(li[i], quad * 4 + r);
  // epilogue: write ctx FRAGMENT-MAJOR for gemm_o:
  // mtile = bm*16+qt, kb = h, slot = (w*2+i)*2 + (j>>1),
  // lane = (((j&1)<<1)|(m16>>3))*16 + quad*4 + r, e = m16&7
  const long cb0 = (((long)(bm * 16 + qt) * 8 + h) * 16);
#pragma unroll
  for (int i = 0; i < 2; i++)
#pragma unroll
    for (int j = 0; j < 4; j++) {
      long off = (cb0 + (w * 2 + i) * 2 + (j >> 1)) * 512 +
                 (((((j & 1) << 1) | (m16 >> 3)) * 16 + quad * 4) * 8) + (m16 & 7);
#pragma unroll
      for (int r = 0; r < 4; r++)
        ctxf[off + r * 8] = f2bf(cacc[i][j][r] * linv[i][r]);
    }
}

extern "C" void kernel_launch(void* const* d_in, const int* in_sizes, int n_in,
                              void* d_out, int out_size, void* d_ws, size_t ws_size,
                              hipStream_t stream) {
  (void)in_sizes; (void)n_in; (void)out_size; (void)ws_size;
  const float* x = (const float*)d_in[0];
  const float* Wq = (const float*)d_in[1];
  const float* bq = (const float*)d_in[2];
  const float* Wkv = (const float*)d_in[3];
  const float* bkv = (const float*)d_in[4];
  const float* Wo = (const float*)d_in[5];
  const float* bo = (const float*)d_in[6];

  char* ws = (char*)d_ws;
  unsigned short* xf     = (unsigned short*)(ws);             // 16 MiB (reused as ctxf)
  unsigned short* Wqf    = (unsigned short*)(ws + 16777216);  // 512 KiB
  unsigned short* Wkvf   = (unsigned short*)(ws + 17301504);  // 512 KiB
  unsigned short* Wof    = (unsigned short*)(ws + 17825792);  // 512 KiB
  unsigned short* Qn_bf  = (unsigned short*)(ws + 18350080);  // 16 MiB
  unsigned short* Kf     = (unsigned short*)(ws + 35127296);  // 16 MiB
  unsigned short* Vf     = (unsigned short*)(ws + 51904512);  // 16 MiB
  unsigned short* ctxf   = xf;  // x dead after gemm_qkv

  cvt_all<<<8960, 256, 0, stream>>>(x, Wq, Wkv, Wo, xf, Wqf, Wkvf, Wof);

  gemm_qkv<<<dim3(128, 8), 256, 0, stream>>>(xf, Wqf, Wkvf, bq, bkv, Qn_bf, Kf, Vf);

  attn_cos<<<dim3(16, 64), 256, 0, stream>>>(Qn_bf, Kf, Vf, ctxf);

  gemm_o<<<dim3(128, 4), 256, 0, stream>>>(ctxf, Wof, bo, (float*)d_out);
}